// Round 11
// baseline (924.211 us; speedup 1.0000x reference)
//
#include <hip/hip_runtime.h>
#include <hip/hip_bf16.h>
#include <math.h>

#define TSEQ 2048
#define DIN  32
#define HID  20
#define G4   80
#define TILE 16
#define NT   (TSEQ / TILE)
#define RT   8                  // rec2 tile (8 steps per prefetch buffer)
#define NRT  (TSEQ / RT)
#define CHUNK 256               // rows per xg block (phase 1)
#define NCHUNK (TSEQ / CHUNK)   // 8
#define L2E  1.44269504088896340736f

#if __has_builtin(__builtin_amdgcn_exp2f)
#define EXP2(x) __builtin_amdgcn_exp2f(x)
#else
#define EXP2(x) __expf((x) * 0.69314718055994531f)
#endif

typedef unsigned int uint2v __attribute__((ext_vector_type(2)));

__device__ __forceinline__ float rl(float v, int l) {
    return __int_as_float(__builtin_amdgcn_readlane(__float_as_int(v), l));
}

__device__ __forceinline__ float sig2(float xs) {   // 1/(1+2^-xs)
    return __builtin_amdgcn_rcpf(1.0f + EXP2(-xs));
}

// cross-half (lane ^ 32) exchange via the gfx950 BUILTIN (hazard-safe; the
// inline-asm version caused the non-deterministic R3/R5/R6/R9 failures).
// With both inputs = v the two results are [lo|lo] and [hi|hi] in some
// order, so r.x + r.y - v = opposite-half value.
__device__ __forceinline__ float xhalf(float v) {
#if __has_builtin(__builtin_amdgcn_permlane32_swap)
    uint2v r = __builtin_amdgcn_permlane32_swap(__float_as_uint(v),
                                                __float_as_uint(v),
                                                false, false);
    return (__uint_as_float(r.x) + __uint_as_float(r.y)) - v;
#else
    return __shfl_xor(v, 32);
#endif
}

__device__ __forceinline__ float samp(const float* mu, const float* rho,
                                      const float* eps, int i) {
    return mu[i] + log1pf(__expf(rho[i])) * eps[i];
}

// ============================ PHASE 1: xg GEMM ============================
// (byte-identical to the R10 passing version)
__global__ __launch_bounds__(64, 1) void xg_kernel(
    const float* __restrict__ x,
    const float* __restrict__ wih_mu, const float* __restrict__ wih_rho, const float* __restrict__ wih_eps,
    const float* __restrict__ bmu,    const float* __restrict__ brho,    const float* __restrict__ beps,
    float* __restrict__ xg_ws)
{
    const int lane = threadIdx.x;
    const int b    = blockIdx.x / NCHUNK;
    const int ch   = blockIdx.x % NCHUNK;
    const float* xu = x + ((size_t)b * TSEQ + (size_t)ch * CHUNK) * DIN;
    float* xgo = xg_ws + ((size_t)b * TSEQ + (size_t)ch * CHUNK) * G4;

    const int cA = lane;
    const int cB = 64 + (lane & 15);
    const float scA = ((cA >= 40 && cA < 60) ? 2.0f : 1.0f) * L2E;
    const float scB = L2E;

    float wA[DIN], wB[DIN];
#pragma unroll
    for (int d = 0; d < DIN; ++d) {
        wA[d] = samp(wih_mu, wih_rho, wih_eps, d * G4 + cA) * scA;
        wB[d] = samp(wih_mu, wih_rho, wih_eps, d * G4 + cB) * scB;
    }
    const float biasA = samp(bmu, brho, beps, cA) * scA;
    const float biasB = samp(bmu, brho, beps, cB) * scB;

    const int posA = ((cA >= 40) ? 40 : 0) + (cA % 20) * 2 + ((cA / 20) & 1);
    const int posB = 40 + (cB % 20) * 2 + 1;

#pragma unroll 4
    for (int s = 0; s < CHUNK; ++s) {
        const float* xs = xu + s * DIN;
        float a0 = 0.f, a1 = 0.f, b0 = 0.f, b1 = 0.f;
#pragma unroll
        for (int d = 0; d < 16; ++d) {
            const float xe = xs[d], xo = xs[d + 16];
            a0 = fmaf(xe, wA[d],      a0);
            a1 = fmaf(xo, wA[d + 16], a1);
            b0 = fmaf(xe, wB[d],      b0);
            b1 = fmaf(xo, wB[d + 16], b1);
        }
        xgo[s * G4 + posA] = biasA + a0 + a1;
        if (lane < 16) xgo[s * G4 + posB] = biasB + b0 + b1;
    }
}

// ================= PHASE 2: recurrence, 2 sequences / wave =================
// Latency-bound chain (~500 cy/step measured in R10) -> interleave two
// independent sequences in one wave's instruction stream; B's instructions
// issue inside A's dependency stalls. Weights shared; only state/buffers
// duplicated. Step formulas byte-preserved from the R10 passing kernel.
__global__ __launch_bounds__(64, 1) void rec2_kernel(
    const float* __restrict__ xg_ws,
    const float* __restrict__ whh_mu, const float* __restrict__ whh_rho, const float* __restrict__ whh_eps,
    const float* __restrict__ wlin,   const float* __restrict__ blin,
    float* __restrict__ out)
{
    __shared__ __align__(16) float hist[2][64 * HID];

    const int lane = threadIdx.x;
    const int b0   = blockIdx.x * 2;
    const int b1   = b0 + 1;
    const int p  = lane >> 5;
    const int k  = lane & 31;
    const int ke = (k < HID) ? k : (HID - 1);
    const int g1 = p * 40 + ke;
    const int g2 = g1 + HID;
    const float aAct = p ? 2.0f : 1.0f;
    const float cAct = 1.0f - aAct;
    const float sc1 = aAct * L2E;
    const float sc2 = L2E;

    float w1[HID], w2[HID];
#pragma unroll
    for (int j = 0; j < HID; ++j) {
        w1[j] = samp(whh_mu, whh_rho, whh_eps, j * G4 + g1) * sc1;
        w2[j] = samp(whh_mu, whh_rho, whh_eps, j * G4 + g2) * sc2;
    }
    const int coff = p * 40 + ke * 2;

    float wl[HID];
#pragma unroll
    for (int j = 0; j < HID; ++j) wl[j] = wlin[j];
    const float bl = blin[0];

    const float* xgA = xg_ws + (size_t)b0 * TSEQ * G4;
    const float* xgB = xg_ws + (size_t)b1 * TSEQ * G4;
    float* outA = out + (size_t)b0 * TSEQ;
    float* outB = out + (size_t)b1 * TSEQ;

    float hA = 0.0f, cA = 0.0f, hB = 0.0f, cB = 0.0f;
    float2 xaA[RT], xbA[RT], xaB[RT], xbB[RT];

    auto loadt = [&](float2* dst, const float* xgb, int kt) {
        const float* rowp = xgb + (size_t)kt * RT * G4 + coff;
#pragma unroll
        for (int s = 0; s < RT; ++s)
            dst[s] = *(const float2*)(rowp + s * G4);
    };

    auto steps = [&](const float2* xrA, const float2* xrB, int kt) {
#pragma unroll
        for (int ti = 0; ti < RT; ++ti) {
            const int t = kt * RT + ti;

            // ---- interleaved h-broadcasts (independent chains) ----
            float hjA[HID], hjB[HID];
#pragma unroll
            for (int j = 0; j < HID; ++j) hjA[j] = rl(hA, j);
#pragma unroll
            for (int j = 0; j < HID; ++j) hjB[j] = rl(hB, j);

            // ---- sequence A dot ----
            float d1aA = xrA[ti].x, d2aA = xrA[ti].y;
            float d1bA = 0.0f, d2bA = 0.0f;
            // ---- sequence B dot ----
            float d1aB = xrB[ti].x, d2aB = xrB[ti].y;
            float d1bB = 0.0f, d2bB = 0.0f;
#pragma unroll
            for (int j = 0; j < HID; j += 2) {
                d1aA = fmaf(hjA[j],     w1[j],     d1aA);
                d2aA = fmaf(hjA[j],     w2[j],     d2aA);
                d1aB = fmaf(hjB[j],     w1[j],     d1aB);
                d2aB = fmaf(hjB[j],     w2[j],     d2aB);
                d1bA = fmaf(hjA[j + 1], w1[j + 1], d1bA);
                d2bA = fmaf(hjA[j + 1], w2[j + 1], d2bA);
                d1bB = fmaf(hjB[j + 1], w1[j + 1], d1bB);
                d2bB = fmaf(hjB[j + 1], w2[j + 1], d2bB);
            }
            const float d1A = d1aA + d1bA, d2A = d2aA + d2bA;
            const float d1B = d1aB + d1bB, d2B = d2aB + d2bB;

            // ---- activations (A and B interleave through the trans unit) ----
            const float s1A   = sig2(d1A);
            const float s1B   = sig2(d1B);
            const float act1A = fmaf(s1A, aAct, cAct);
            const float act1B = fmaf(s1B, aAct, cAct);
            const float act2A = sig2(d2A);
            const float act2B = sig2(d2B);

            const float og1A = xhalf(act1A);
            const float og1B = xhalf(act1B);
            const float og2A = xhalf(act2A);
            const float og2B = xhalf(act2B);

            cA = fmaf(act2A, cA, act1A * og1A);
            cB = fmaf(act2B, cB, act1B * og1B);
            const float tcA = fmaf(2.0f, sig2(cA * (2.0f * L2E)), -1.0f);
            const float tcB = fmaf(2.0f, sig2(cB * (2.0f * L2E)), -1.0f);
            hA = og2A * tcA;
            hB = og2B * tcB;

            if (lane < HID) {
                hist[0][(t & 63) * HID + lane] = hA;
                hist[1][(t & 63) * HID + lane] = hB;
            }

            if ((t & 63) == 63) {                   // flush both sequences
#pragma unroll
                for (int q = 0; q < 2; ++q) {
                    const float4* hr = (const float4*)&hist[q][lane * HID];
                    const float4 r0 = hr[0], r1 = hr[1], r2 = hr[2], r3 = hr[3], r4 = hr[4];
                    float acc = bl;
                    acc = fmaf(r0.x, wl[0],  acc); acc = fmaf(r0.y, wl[1],  acc);
                    acc = fmaf(r0.z, wl[2],  acc); acc = fmaf(r0.w, wl[3],  acc);
                    acc = fmaf(r1.x, wl[4],  acc); acc = fmaf(r1.y, wl[5],  acc);
                    acc = fmaf(r1.z, wl[6],  acc); acc = fmaf(r1.w, wl[7],  acc);
                    acc = fmaf(r2.x, wl[8],  acc); acc = fmaf(r2.y, wl[9],  acc);
                    acc = fmaf(r2.z, wl[10], acc); acc = fmaf(r2.w, wl[11], acc);
                    acc = fmaf(r3.x, wl[12], acc); acc = fmaf(r3.y, wl[13], acc);
                    acc = fmaf(r3.z, wl[14], acc); acc = fmaf(r3.w, wl[15], acc);
                    acc = fmaf(r4.x, wl[16], acc); acc = fmaf(r4.y, wl[17], acc);
                    acc = fmaf(r4.z, wl[18], acc); acc = fmaf(r4.w, wl[19], acc);
                    float* op = q ? outB : outA;
                    op[(t - 63) + lane] = acc;
                }
            }
        }
    };

    loadt(xaA, xgA, 0);
    loadt(xaB, xgB, 0);
    for (int kt = 0; kt < NRT; kt += 2) {
        loadt(xbA, xgA, kt + 1);
        loadt(xbB, xgB, kt + 1);
        steps(xaA, xaB, kt);
        if (kt + 2 < NRT) {
            loadt(xaA, xgA, kt + 2);
            loadt(xaB, xgB, kt + 2);
        }
        steps(xbA, xbB, kt + 1);
    }
}

// ===================== FALLBACK: R7 fused (proven 435us) =====================
__global__ __launch_bounds__(128, 1) void blstm_fused(
    const float* __restrict__ x,
    const float* __restrict__ wih_mu, const float* __restrict__ wih_rho, const float* __restrict__ wih_eps,
    const float* __restrict__ whh_mu, const float* __restrict__ whh_rho, const float* __restrict__ whh_eps,
    const float* __restrict__ bmu,    const float* __restrict__ brho,    const float* __restrict__ beps,
    const float* __restrict__ wlin,   const float* __restrict__ blin,
    float* __restrict__ out)
{
    __shared__ __align__(16) float lds_xg[2][TILE * G4];
    __shared__ __align__(16) float lds_x[TILE * DIN];
    __shared__ __align__(16) float hist[64 * HID];

    const int tid  = threadIdx.x;
    const int lane = tid & 63;
    const int b    = blockIdx.x;
    const float* xrow = x + (size_t)b * TSEQ * DIN;
    float* outp = out + (size_t)b * TSEQ;

    if (tid < 64) {
        const int p  = lane >> 5;
        const int k  = lane & 31;
        const int ke = (k < HID) ? k : (HID - 1);
        const int g1 = p * 40 + ke;
        const int g2 = g1 + HID;
        const float aAct = p ? 2.0f : 1.0f;
        const float cAct = 1.0f - aAct;
        const float sc1 = aAct * L2E;
        const float sc2 = L2E;

        float w1[HID], w2[HID];
#pragma unroll
        for (int j = 0; j < HID; ++j) {
            w1[j] = samp(whh_mu, whh_rho, whh_eps, j * G4 + g1) * sc1;
            w2[j] = samp(whh_mu, whh_rho, whh_eps, j * G4 + g2) * sc2;
        }
        const int coff = p * 40 + ke * 2;

        float h = 0.0f, c = 0.0f;
        for (int kt = 0; kt < NT; ++kt) {
            __syncthreads();
            const float* xg = lds_xg[kt & 1];
            float2 xgr[TILE];
#pragma unroll
            for (int r = 0; r < TILE; ++r)
                xgr[r] = *(const float2*)&xg[r * G4 + coff];

#pragma unroll
            for (int ti = 0; ti < TILE; ++ti) {
                float hj[HID];
#pragma unroll
                for (int j = 0; j < HID; ++j) hj[j] = rl(h, j);

                float d1a = xgr[ti].x, d2a = xgr[ti].y;
                float d1b = 0.0f, d2b = 0.0f;
#pragma unroll
                for (int j = 0; j < HID; j += 2) {
                    d1a = fmaf(hj[j],     w1[j],     d1a);
                    d2a = fmaf(hj[j],     w2[j],     d2a);
                    d1b = fmaf(hj[j + 1], w1[j + 1], d1b);
                    d2b = fmaf(hj[j + 1], w2[j + 1], d2b);
                }
                const float d1 = d1a + d1b;
                const float d2 = d2a + d2b;
                const float s1   = sig2(d1);
                const float act1 = fmaf(s1, aAct, cAct);
                const float act2 = sig2(d2);
                const float og1 = xhalf(act1);
                const float og2 = xhalf(act2);
                c = fmaf(act2, c, act1 * og1);
                const float tc = fmaf(2.0f, sig2(c * (2.0f * L2E)), -1.0f);
                h = og2 * tc;
                const int t = kt * TILE + ti;
                if (lane < HID) hist[(t & 63) * HID + lane] = h;
            }
        }
        __syncthreads();
    } else {
        const int cA = lane;
        const int cB = 64 + (lane & 15);
        const float scA = ((cA >= 40 && cA < 60) ? 2.0f : 1.0f) * L2E;
        const float scB = L2E;

        float wA[DIN], wB[DIN];
#pragma unroll
        for (int d = 0; d < DIN; ++d) {
            wA[d] = samp(wih_mu, wih_rho, wih_eps, d * G4 + cA) * scA;
            wB[d] = samp(wih_mu, wih_rho, wih_eps, d * G4 + cB) * scB;
        }
        const float biasA = samp(bmu, brho, beps, cA) * scA;
        const float biasB = samp(bmu, brho, beps, cB) * scB;
        const int posA = ((cA >= 40) ? 40 : 0) + (cA % 20) * 2 + ((cA / 20) & 1);
        const int posB = ((cB >= 40) ? 40 : 0) + (cB % 20) * 2 + ((cB / 20) & 1);
        const int qs   = (lane >> 4) * 4;

        float wl[HID];
#pragma unroll
        for (int j = 0; j < HID; ++j) wl[j] = wlin[j];
        const float bl = blin[0];

        auto produce = [&](int kt) {
            const float* xu = xrow + kt * TILE * DIN;
            float* xgb = lds_xg[kt & 1];
            {
                const float4* src = (const float4*)xu;
                float4 v0 = src[lane * 2 + 0];
                float4 v1 = src[lane * 2 + 1];
                ((float4*)lds_x)[lane * 2 + 0] = v0;
                ((float4*)lds_x)[lane * 2 + 1] = v1;
            }
#pragma unroll
            for (int s = 0; s < TILE; ++s) {
                float a0 = 0.0f, a1 = 0.0f;
#pragma unroll
                for (int d = 0; d < 16; ++d) {
                    a0 = fmaf(xu[s * DIN + d],      wA[d],      a0);
                    a1 = fmaf(xu[s * DIN + d + 16], wA[d + 16], a1);
                }
                xgb[s * G4 + posA] = biasA + a0 + a1;
            }
#pragma unroll
            for (int jj = 0; jj < 4; ++jj) {
                const int s = qs + jj;
                const float4* xr = (const float4*)&lds_x[s * DIN];
                float a0 = 0.0f, a1 = 0.0f;
#pragma unroll
                for (int q = 0; q < 4; ++q) {
                    const float4 u0 = xr[q], u1 = xr[q + 4];
                    a0 = fmaf(u0.x, wB[q * 4 + 0],      a0);
                    a0 = fmaf(u0.y, wB[q * 4 + 1],      a0);
                    a0 = fmaf(u0.z, wB[q * 4 + 2],      a0);
                    a0 = fmaf(u0.w, wB[q * 4 + 3],      a0);
                    a1 = fmaf(u1.x, wB[16 + q * 4 + 0], a1);
                    a1 = fmaf(u1.y, wB[16 + q * 4 + 1], a1);
                    a1 = fmaf(u1.z, wB[16 + q * 4 + 2], a1);
                    a1 = fmaf(u1.w, wB[16 + q * 4 + 3], a1);
                }
                xgb[s * G4 + posB] = biasB + a0 + a1;
            }
        };

        auto flush = [&](int ft) {
            if (lane < TILE) {
                const int t = ft * TILE + lane;
                const float4* hr = (const float4*)&hist[(t & 63) * HID];
                const float4 r0 = hr[0], r1 = hr[1], r2 = hr[2], r3 = hr[3], r4 = hr[4];
                float acc = bl;
                acc = fmaf(r0.x, wl[0],  acc); acc = fmaf(r0.y, wl[1],  acc);
                acc = fmaf(r0.z, wl[2],  acc); acc = fmaf(r0.w, wl[3],  acc);
                acc = fmaf(r1.x, wl[4],  acc); acc = fmaf(r1.y, wl[5],  acc);
                acc = fmaf(r1.z, wl[6],  acc); acc = fmaf(r1.w, wl[7],  acc);
                acc = fmaf(r2.x, wl[8],  acc); acc = fmaf(r2.y, wl[9],  acc);
                acc = fmaf(r2.z, wl[10], acc); acc = fmaf(r2.w, wl[11], acc);
                acc = fmaf(r3.x, wl[12], acc); acc = fmaf(r3.y, wl[13], acc);
                acc = fmaf(r3.z, wl[14], acc); acc = fmaf(r3.w, wl[15], acc);
                acc = fmaf(r4.x, wl[16], acc); acc = fmaf(r4.y, wl[17], acc);
                acc = fmaf(r4.z, wl[18], acc); acc = fmaf(r4.w, wl[19], acc);
                outp[t] = acc;
            }
        };

        produce(0);
        for (int kt = 0; kt < NT; ++kt) {
            __syncthreads();
            if (kt + 1 < NT) produce(kt + 1);
            if (kt >= 1)     flush(kt - 1);
        }
        __syncthreads();
        flush(NT - 1);
    }
}

extern "C" void kernel_launch(void* const* d_in, const int* in_sizes, int n_in,
                              void* d_out, int out_size, void* d_ws, size_t ws_size,
                              hipStream_t stream) {
    const float* x       = (const float*)d_in[0];
    const float* wih_mu  = (const float*)d_in[1];
    const float* wih_rho = (const float*)d_in[2];
    const float* wih_eps = (const float*)d_in[3];
    const float* whh_mu  = (const float*)d_in[4];
    const float* whh_rho = (const float*)d_in[5];
    const float* whh_eps = (const float*)d_in[6];
    const float* bmu     = (const float*)d_in[7];
    const float* brho    = (const float*)d_in[8];
    const float* beps    = (const float*)d_in[9];
    const float* wlin    = (const float*)d_in[10];
    const float* blin    = (const float*)d_in[11];
    float* out = (float*)d_out;

    const int B = in_sizes[0] / (TSEQ * DIN);   // 256
    const size_t need = (size_t)B * TSEQ * G4 * sizeof(float);  // ~168 MB

    if (ws_size >= need && (B & 1) == 0) {
        xg_kernel<<<B * NCHUNK, 64, 0, stream>>>(x, wih_mu, wih_rho, wih_eps,
                                                 bmu, brho, beps, (float*)d_ws);
        rec2_kernel<<<B / 2, 64, 0, stream>>>((const float*)d_ws,
                                              whh_mu, whh_rho, whh_eps,
                                              wlin, blin, out);
    } else {
        blstm_fused<<<B, 128, 0, stream>>>(x, wih_mu, wih_rho, wih_eps,
                                           whh_mu, whh_rho, whh_eps,
                                           bmu, brho, beps, wlin, blin, out);
    }
}

// Round 12
// 666.674 us; speedup vs baseline: 1.3863x; 1.3863x over previous
//
#include <hip/hip_runtime.h>
#include <hip/hip_bf16.h>
#include <math.h>

#define TSEQ 2048
#define DIN  32
#define HID  20
#define G4   80
#define TILE 16
#define NT   (TSEQ / TILE)
#define HSTR 68                 // padded hist row stride (floats); 68*4B = 16B-aligned rows
#define L2E  1.44269504088896340736f

typedef float v2f __attribute__((ext_vector_type(2)));
typedef unsigned int uint2v __attribute__((ext_vector_type(2)));

#if __has_builtin(__builtin_amdgcn_exp2f)
#define EXP2(x) __builtin_amdgcn_exp2f(x)
#else
#define EXP2(x) __expf((x) * 0.69314718055994531f)
#endif

__device__ __forceinline__ float rl(float v, int l) {
    return __int_as_float(__builtin_amdgcn_readlane(__float_as_int(v), l));
}

__device__ __forceinline__ float sig2(float xs) {   // 1/(1+2^-xs), xs pre-scaled by log2e
    return __builtin_amdgcn_rcpf(1.0f + EXP2(-xs));
}

// cross-half (lane ^ 32) exchange via the gfx950 BUILTIN (hazard-safe — the
// inline-asm form caused the non-deterministic R3/R5/R6/R9 failures; R10
// confirmed the builtin fixes it). With both inputs = v the two results are
// the [lo|lo] and [hi|hi] broadcasts in some order: r.x + r.y - v = opposite half.
__device__ __forceinline__ float xhalf(float v) {
#if __has_builtin(__builtin_amdgcn_permlane32_swap)
    uint2v r = __builtin_amdgcn_permlane32_swap(__float_as_uint(v),
                                                __float_as_uint(v),
                                                false, false);
    return (__uint_as_float(r.x) + __uint_as_float(r.y)) - v;
#else
    return __shfl_xor(v, 32);
#endif
}

__device__ __forceinline__ float samp(const float* mu, const float* rho,
                                      const float* eps, int i) {
    return mu[i] + log1pf(__expf(rho[i])) * eps[i];
}

// Fused kernel, R7-proven barrier structure. Consumer instruction stream
// slimmed for the per-wave issue cadence (~4-5 cy/inst for a lone wave):
//  - v_pk_fma_f32 dot (40 fma -> 20 pk_fma + 1 pk_add)
//  - c kept in exp2 domain (c' = 2*L2E*c): deletes the per-step mul
//  - unconditional padded hist write: deletes the lane<20 exec-mask dance
__global__ __launch_bounds__(128, 1) void blstm_fused(
    const float* __restrict__ x,
    const float* __restrict__ wih_mu, const float* __restrict__ wih_rho, const float* __restrict__ wih_eps,
    const float* __restrict__ whh_mu, const float* __restrict__ whh_rho, const float* __restrict__ whh_eps,
    const float* __restrict__ bmu,    const float* __restrict__ brho,    const float* __restrict__ beps,
    const float* __restrict__ wlin,   const float* __restrict__ blin,
    float* __restrict__ out)
{
    __shared__ __align__(16) float lds_xg[2][TILE * G4];  // double-buffered xg tiles (permuted)
    __shared__ __align__(16) float hist[64 * HSTR];       // padded h ring

    const int tid  = threadIdx.x;
    const int lane = tid & 63;
    const int b    = blockIdx.x;
    const float* xrow = x + (size_t)b * TSEQ * DIN;
    float* outp = out + (size_t)b * TSEQ;

    if (tid < 64) {
        // ======================= CONSUMER (recurrence) =======================
        const int p  = lane >> 5;                  // 0: (i,f) cols; 1: (g,o) cols
        const int k  = lane & 31;
        const int ke = (k < HID) ? k : (HID - 1);  // junk lanes mirror unit 19
        const int g1 = p * 40 + ke;                // i_k or g_k
        const int g2 = g1 + HID;                   // f_k or o_k
        const float sc1 = (p ? 2.0f : 1.0f) * L2E; // pre-act scale (as producer's)
        const float sc2 = L2E;
        // act1 constants, with 2*L2E folded into the HIGH-lane tanh output:
        //   low:  act1 = sig(i)            (aAct2=1, cAct2=0)
        //   high: act1 = 2*L2E*tanh(g) = s1*4*L2E - 2*L2E
        const float aAct2 = p ? (4.0f * L2E) : 1.0f;
        const float cAct2 = p ? (-2.0f * L2E) : 0.0f;

        // packed weight pairs: w12e[jj] = {w1[2jj], w2[2jj]}, w12o odd
        v2f w12e[HID / 2], w12o[HID / 2];
#pragma unroll
        for (int jj = 0; jj < HID / 2; ++jj) {
            const int je = 2 * jj, jo = 2 * jj + 1;
            w12e[jj] = (v2f){ samp(whh_mu, whh_rho, whh_eps, je * G4 + g1) * sc1,
                              samp(whh_mu, whh_rho, whh_eps, je * G4 + g2) * sc2 };
            w12o[jj] = (v2f){ samp(whh_mu, whh_rho, whh_eps, jo * G4 + g1) * sc1,
                              samp(whh_mu, whh_rho, whh_eps, jo * G4 + g2) * sc2 };
        }
        const int coff = p * 40 + ke * 2;          // float2 slot in permuted xg row

        float h = 0.0f, c = 0.0f;                  // c is c' = 2*L2E*c_true
        for (int kt = 0; kt < NT; ++kt) {
            __syncthreads();                       // tile kt ready
            const float* xg = lds_xg[kt & 1];
            v2f xgr[TILE];
#pragma unroll
            for (int r = 0; r < TILE; ++r)
                xgr[r] = *(const v2f*)&xg[r * G4 + coff];

#pragma unroll
            for (int ti = 0; ti < TILE; ++ti) {
                float hj[HID];
#pragma unroll
                for (int j = 0; j < HID; ++j) hj[j] = rl(h, j);

                v2f d12a = xgr[ti];
                v2f d12b = (v2f){0.0f, 0.0f};
#pragma unroll
                for (int jj = 0; jj < HID / 2; ++jj) {
                    d12a = __builtin_elementwise_fma(
                        (v2f){hj[2 * jj], hj[2 * jj]}, w12e[jj], d12a);
                    d12b = __builtin_elementwise_fma(
                        (v2f){hj[2 * jj + 1], hj[2 * jj + 1]}, w12o[jj], d12b);
                }
                const v2f d12 = d12a + d12b;

                const float s1   = sig2(d12.x);             // sig(i) / sig(2g)
                const float act1 = fmaf(s1, aAct2, cAct2);  // sig(i) / 2L2E*tanh(g)
                const float act2 = sig2(d12.y);             // sig(f) / sig(o)

                const float og1 = xhalf(act1);              // low: 2L2E*tanh(g)
                const float og2 = xhalf(act2);              // low: sig(o)

                c = fmaf(act2, c, act1 * og1);              // c' = f*c' + i*2L2E*tanh(g)
                const float tc = fmaf(2.0f, sig2(c), -1.0f);// tanh(c_true)
                h = og2 * tc;                               // low: o * tanh(c)

                const int t = kt * TILE + ti;
                hist[(t & 63) * HSTR + lane] = h;           // unconditional, padded
            }
        }
        __syncthreads();                           // expose last tile's hist
    } else {
        // ======================= PRODUCER (xg + output) =======================
        const int cA = lane;                       // columns 0..63
        const int cB = 64 + (lane & 15);           // columns 64..79 ('o' tail)
        const float scA = ((cA >= 40 && cA < 60) ? 2.0f : 1.0f) * L2E;
        const float scB = L2E;

        // packed column pair {cA, cB}
        v2f wAB[DIN];
#pragma unroll
        for (int d = 0; d < DIN; ++d) {
            wAB[d] = (v2f){ samp(wih_mu, wih_rho, wih_eps, d * G4 + cA) * scA,
                            samp(wih_mu, wih_rho, wih_eps, d * G4 + cB) * scB };
        }
        const v2f bias12 = (v2f){ samp(bmu, brho, beps, cA) * scA,
                                  samp(bmu, brho, beps, cB) * scB };

        const int posA = ((cA >= 40) ? 40 : 0) + (cA % 20) * 2 + ((cA / 20) & 1);
        const int posB = 40 + (cB % 20) * 2 + 1;   // 'o' columns

        float wl[HID];
#pragma unroll
        for (int j = 0; j < HID; ++j) wl[j] = wlin[j];
        const float bl = blin[0];

        // produce tile kt into lds_xg[kt&1]; x via uniform scalar loads
        auto produce = [&](int kt) {
            const float* xu = xrow + kt * TILE * DIN;
            float* xgb = lds_xg[kt & 1];
#pragma unroll
            for (int s = 0; s < TILE; ++s) {
                const float* xs = xu + s * DIN;    // wave-uniform -> s_loads
                v2f acc0 = (v2f){0.0f, 0.0f};
                v2f acc1 = (v2f){0.0f, 0.0f};
#pragma unroll
                for (int d = 0; d < 16; ++d) {
                    acc0 = __builtin_elementwise_fma(
                        (v2f){xs[d], xs[d]}, wAB[d], acc0);
                    acc1 = __builtin_elementwise_fma(
                        (v2f){xs[d + 16], xs[d + 16]}, wAB[d + 16], acc1);
                }
                const v2f r = (acc0 + acc1) + bias12;
                xgb[s * G4 + posA] = r.x;
                // lanes {l, l+16, l+32, l+48} write the identical value to the
                // same posB slot -- benign same-value race, saves the exec mask
                xgb[s * G4 + posB] = r.y;
            }
        };

        // flush outputs for tile ft (hist already complete & barrier-visible)
        auto flush = [&](int ft) {
            if (lane < TILE) {
                const int t = ft * TILE + lane;
                const float4* hr = (const float4*)&hist[(t & 63) * HSTR];
                const float4 r0 = hr[0], r1 = hr[1], r2 = hr[2], r3 = hr[3], r4 = hr[4];
                float acc = bl;
                acc = fmaf(r0.x, wl[0],  acc); acc = fmaf(r0.y, wl[1],  acc);
                acc = fmaf(r0.z, wl[2],  acc); acc = fmaf(r0.w, wl[3],  acc);
                acc = fmaf(r1.x, wl[4],  acc); acc = fmaf(r1.y, wl[5],  acc);
                acc = fmaf(r1.z, wl[6],  acc); acc = fmaf(r1.w, wl[7],  acc);
                acc = fmaf(r2.x, wl[8],  acc); acc = fmaf(r2.y, wl[9],  acc);
                acc = fmaf(r2.z, wl[10], acc); acc = fmaf(r2.w, wl[11], acc);
                acc = fmaf(r3.x, wl[12], acc); acc = fmaf(r3.y, wl[13], acc);
                acc = fmaf(r3.z, wl[14], acc); acc = fmaf(r3.w, wl[15], acc);
                acc = fmaf(r4.x, wl[16], acc); acc = fmaf(r4.y, wl[17], acc);
                acc = fmaf(r4.z, wl[18], acc); acc = fmaf(r4.w, wl[19], acc);
                outp[t] = acc;
            }
        };

        produce(0);
        for (int kt = 0; kt < NT; ++kt) {
            __syncthreads();                       // release tile kt
            if (kt + 1 < NT) produce(kt + 1);
            if (kt >= 1)     flush(kt - 1);
        }
        __syncthreads();                           // consumer's last tile visible
        flush(NT - 1);
    }
}

extern "C" void kernel_launch(void* const* d_in, const int* in_sizes, int n_in,
                              void* d_out, int out_size, void* d_ws, size_t ws_size,
                              hipStream_t stream) {
    const float* x       = (const float*)d_in[0];
    const float* wih_mu  = (const float*)d_in[1];
    const float* wih_rho = (const float*)d_in[2];
    const float* wih_eps = (const float*)d_in[3];
    const float* whh_mu  = (const float*)d_in[4];
    const float* whh_rho = (const float*)d_in[5];
    const float* whh_eps = (const float*)d_in[6];
    const float* bmu     = (const float*)d_in[7];
    const float* brho    = (const float*)d_in[8];
    const float* beps    = (const float*)d_in[9];
    const float* wlin    = (const float*)d_in[10];
    const float* blin    = (const float*)d_in[11];
    float* out = (float*)d_out;

    const int B = in_sizes[0] / (TSEQ * DIN);   // 256

    blstm_fused<<<B, 128, 0, stream>>>(x, wih_mu, wih_rho, wih_eps,
                                       whh_mu, whh_rho, whh_eps,
                                       bmu, brho, beps, wlin, blin, out);
}

// Round 13
// 396.217 us; speedup vs baseline: 2.3326x; 1.6826x over previous
//
#include <hip/hip_runtime.h>
#include <hip/hip_bf16.h>
#include <math.h>

#define TSEQ 2048
#define DIN  32
#define HID  20
#define G4   80
#define TILE 16
#define NT   (TSEQ / TILE)
#define HSTR 68                 // padded hist row stride (floats), 16B-aligned rows
#define L2E  1.44269504088896340736f

typedef float v2f __attribute__((ext_vector_type(2)));
typedef unsigned int uint2v __attribute__((ext_vector_type(2)));

#if __has_builtin(__builtin_amdgcn_exp2f)
#define EXP2(x) __builtin_amdgcn_exp2f(x)
#else
#define EXP2(x) __expf((x) * 0.69314718055994531f)
#endif

__device__ __forceinline__ float rl(float v, int l) {
    return __int_as_float(__builtin_amdgcn_readlane(__float_as_int(v), l));
}

__device__ __forceinline__ float sig2(float xs) {   // 1/(1+2^-xs), xs pre-scaled by log2e
    return __builtin_amdgcn_rcpf(1.0f + EXP2(-xs));
}

// cross-half (lane ^ 32) exchange via the gfx950 BUILTIN (hazard-safe; the
// inline-asm form caused the non-deterministic R3/R5/R6/R9 failures — R10
// confirmed the builtin fix). r.x + r.y - v = opposite-half value.
__device__ __forceinline__ float xhalf(float v) {
#if __has_builtin(__builtin_amdgcn_permlane32_swap)
    uint2v r = __builtin_amdgcn_permlane32_swap(__float_as_uint(v),
                                                __float_as_uint(v),
                                                false, false);
    return (__uint_as_float(r.x) + __uint_as_float(r.y)) - v;
#else
    return __shfl_xor(v, 32);
#endif
}

__device__ __forceinline__ float samp(const float* mu, const float* rho,
                                      const float* eps, int i) {
    return mu[i] + log1pf(__expf(rho[i])) * eps[i];
}

// R7 producer (lds_x staging = L1/L2 prewarm for the uniform scalar loads;
// R4/R12 proved removing it makes the producer the critical path) +
// R12 consumer (pk dot, exp2-domain c, unconditional padded hist write).
__global__ __launch_bounds__(128, 1) void blstm_fused(
    const float* __restrict__ x,
    const float* __restrict__ wih_mu, const float* __restrict__ wih_rho, const float* __restrict__ wih_eps,
    const float* __restrict__ whh_mu, const float* __restrict__ whh_rho, const float* __restrict__ whh_eps,
    const float* __restrict__ bmu,    const float* __restrict__ brho,    const float* __restrict__ beps,
    const float* __restrict__ wlin,   const float* __restrict__ blin,
    float* __restrict__ out)
{
    __shared__ __align__(16) float lds_xg[2][TILE * G4];  // double-buffered xg tiles (permuted)
    __shared__ __align__(16) float lds_x[TILE * DIN];     // producer-private x stage
    __shared__ __align__(16) float hist[64 * HSTR];       // padded h ring

    const int tid  = threadIdx.x;
    const int lane = tid & 63;
    const int b    = blockIdx.x;
    const float* xrow = x + (size_t)b * TSEQ * DIN;
    float* outp = out + (size_t)b * TSEQ;

    if (tid < 64) {
        // ================= CONSUMER (R12-proven, pk dot) =================
        const int p  = lane >> 5;                  // 0: (i,f) cols; 1: (g,o) cols
        const int k  = lane & 31;
        const int ke = (k < HID) ? k : (HID - 1);  // junk lanes mirror unit 19
        const int g1 = p * 40 + ke;                // i_k or g_k
        const int g2 = g1 + HID;                   // f_k or o_k
        const float sc1 = (p ? 2.0f : 1.0f) * L2E;
        const float sc2 = L2E;
        // act1 constants with 2*L2E folded into the HIGH-lane tanh output:
        //   low:  act1 = sig(i);  high: act1 = 2*L2E*tanh(g)
        const float aAct2 = p ? (4.0f * L2E) : 1.0f;
        const float cAct2 = p ? (-2.0f * L2E) : 0.0f;

        v2f w12e[HID / 2], w12o[HID / 2];
#pragma unroll
        for (int jj = 0; jj < HID / 2; ++jj) {
            const int je = 2 * jj, jo = 2 * jj + 1;
            w12e[jj] = (v2f){ samp(whh_mu, whh_rho, whh_eps, je * G4 + g1) * sc1,
                              samp(whh_mu, whh_rho, whh_eps, je * G4 + g2) * sc2 };
            w12o[jj] = (v2f){ samp(whh_mu, whh_rho, whh_eps, jo * G4 + g1) * sc1,
                              samp(whh_mu, whh_rho, whh_eps, jo * G4 + g2) * sc2 };
        }
        const int coff = p * 40 + ke * 2;

        float h = 0.0f, c = 0.0f;                  // c is c' = 2*L2E*c_true
        for (int kt = 0; kt < NT; ++kt) {
            __syncthreads();                       // tile kt ready
            const float* xg = lds_xg[kt & 1];
            v2f xgr[TILE];
#pragma unroll
            for (int r = 0; r < TILE; ++r)
                xgr[r] = *(const v2f*)&xg[r * G4 + coff];

#pragma unroll
            for (int ti = 0; ti < TILE; ++ti) {
                float hj[HID];
#pragma unroll
                for (int j = 0; j < HID; ++j) hj[j] = rl(h, j);

                v2f d12a = xgr[ti];
                v2f d12b = (v2f){0.0f, 0.0f};
#pragma unroll
                for (int jj = 0; jj < HID / 2; ++jj) {
                    d12a = __builtin_elementwise_fma(
                        (v2f){hj[2 * jj], hj[2 * jj]}, w12e[jj], d12a);
                    d12b = __builtin_elementwise_fma(
                        (v2f){hj[2 * jj + 1], hj[2 * jj + 1]}, w12o[jj], d12b);
                }
                const v2f d12 = d12a + d12b;

                const float s1   = sig2(d12.x);             // sig(i) / sig(2g)
                const float act1 = fmaf(s1, aAct2, cAct2);  // sig(i) / 2L2E*tanh(g)
                const float act2 = sig2(d12.y);             // sig(f) / sig(o)

                const float og1 = xhalf(act1);              // low: 2L2E*tanh(g)
                const float og2 = xhalf(act2);              // low: sig(o)

                c = fmaf(act2, c, act1 * og1);              // c' = f*c' + i*2L2E*tanh(g)
                const float tc = fmaf(2.0f, sig2(c), -1.0f);// tanh(c_true)
                h = og2 * tc;                               // low: o * tanh(c)

                const int t = kt * TILE + ti;
                hist[(t & 63) * HSTR + lane] = h;           // unconditional, padded
            }
        }
        __syncthreads();                           // expose last tile's hist
    } else {
        // ================= PRODUCER (R7-proven, byte-identical) =================
        const int cA = lane;                       // columns 0..63
        const int cB = 64 + (lane & 15);           // columns 64..79 ('o' tail)
        const float scA = ((cA >= 40 && cA < 60) ? 2.0f : 1.0f) * L2E;
        const float scB = L2E;

        float wA[DIN], wB[DIN];
#pragma unroll
        for (int d = 0; d < DIN; ++d) {
            wA[d] = samp(wih_mu, wih_rho, wih_eps, d * G4 + cA) * scA;
            wB[d] = samp(wih_mu, wih_rho, wih_eps, d * G4 + cB) * scB;
        }
        const float biasA = samp(bmu, brho, beps, cA) * scA;
        const float biasB = samp(bmu, brho, beps, cB) * scB;

        const int posA = ((cA >= 40) ? 40 : 0) + (cA % 20) * 2 + ((cA / 20) & 1);
        const int posB = ((cB >= 40) ? 40 : 0) + (cB % 20) * 2 + ((cB / 20) & 1);
        const int qs   = (lane >> 4) * 4;          // dotB step group

        float wl[HID];
#pragma unroll
        for (int j = 0; j < HID; ++j) wl[j] = wlin[j];
        const float bl = blin[0];

        auto produce = [&](int kt) {
            const float* xu = xrow + kt * TILE * DIN;
            float* xgb = lds_xg[kt & 1];
            // stage x tile (coalesced float4 -> L1/L2 prewarm + dotB source)
            {
                const float4* src = (const float4*)xu;
                float4 v0 = src[lane * 2 + 0];
                float4 v1 = src[lane * 2 + 1];
                ((float4*)lds_x)[lane * 2 + 0] = v0;
                ((float4*)lds_x)[lane * 2 + 1] = v1;
            }
            // dotA: uniform x (scalarizable s_loads), 16 steps, 64 columns
#pragma unroll
            for (int s = 0; s < TILE; ++s) {
                float a0 = 0.0f, a1 = 0.0f;
#pragma unroll
                for (int d = 0; d < 16; ++d) {
                    a0 = fmaf(xu[s * DIN + d],      wA[d],      a0);
                    a1 = fmaf(xu[s * DIN + d + 16], wA[d + 16], a1);
                }
                xgb[s * G4 + posA] = biasA + a0 + a1;
            }
            // dotB: 16 extra columns, 4 steps per lane, x from LDS
#pragma unroll
            for (int jj = 0; jj < 4; ++jj) {
                const int s = qs + jj;
                const float4* xr = (const float4*)&lds_x[s * DIN];
                float a0 = 0.0f, a1 = 0.0f;
#pragma unroll
                for (int q = 0; q < 4; ++q) {
                    const float4 u0 = xr[q], u1 = xr[q + 4];
                    a0 = fmaf(u0.x, wB[q * 4 + 0],      a0);
                    a0 = fmaf(u0.y, wB[q * 4 + 1],      a0);
                    a0 = fmaf(u0.z, wB[q * 4 + 2],      a0);
                    a0 = fmaf(u0.w, wB[q * 4 + 3],      a0);
                    a1 = fmaf(u1.x, wB[16 + q * 4 + 0], a1);
                    a1 = fmaf(u1.y, wB[16 + q * 4 + 1], a1);
                    a1 = fmaf(u1.z, wB[16 + q * 4 + 2], a1);
                    a1 = fmaf(u1.w, wB[16 + q * 4 + 3], a1);
                }
                xgb[s * G4 + posB] = biasB + a0 + a1;
            }
        };

        auto flush = [&](int ft) {
            if (lane < TILE) {
                const int t = ft * TILE + lane;
                const float4* hr = (const float4*)&hist[(t & 63) * HSTR];
                const float4 r0 = hr[0], r1 = hr[1], r2 = hr[2], r3 = hr[3], r4 = hr[4];
                float acc = bl;
                acc = fmaf(r0.x, wl[0],  acc); acc = fmaf(r0.y, wl[1],  acc);
                acc = fmaf(r0.z, wl[2],  acc); acc = fmaf(r0.w, wl[3],  acc);
                acc = fmaf(r1.x, wl[4],  acc); acc = fmaf(r1.y, wl[5],  acc);
                acc = fmaf(r1.z, wl[6],  acc); acc = fmaf(r1.w, wl[7],  acc);
                acc = fmaf(r2.x, wl[8],  acc); acc = fmaf(r2.y, wl[9],  acc);
                acc = fmaf(r2.z, wl[10], acc); acc = fmaf(r2.w, wl[11], acc);
                acc = fmaf(r3.x, wl[12], acc); acc = fmaf(r3.y, wl[13], acc);
                acc = fmaf(r3.z, wl[14], acc); acc = fmaf(r3.w, wl[15], acc);
                acc = fmaf(r4.x, wl[16], acc); acc = fmaf(r4.y, wl[17], acc);
                acc = fmaf(r4.z, wl[18], acc); acc = fmaf(r4.w, wl[19], acc);
                outp[t] = acc;
            }
        };

        produce(0);
        for (int kt = 0; kt < NT; ++kt) {
            __syncthreads();                       // release tile kt
            if (kt + 1 < NT) produce(kt + 1);
            if (kt >= 1)     flush(kt - 1);
        }
        __syncthreads();                           // consumer's last tile visible
        flush(NT - 1);
    }
}

extern "C" void kernel_launch(void* const* d_in, const int* in_sizes, int n_in,
                              void* d_out, int out_size, void* d_ws, size_t ws_size,
                              hipStream_t stream) {
    const float* x       = (const float*)d_in[0];
    const float* wih_mu  = (const float*)d_in[1];
    const float* wih_rho = (const float*)d_in[2];
    const float* wih_eps = (const float*)d_in[3];
    const float* whh_mu  = (const float*)d_in[4];
    const float* whh_rho = (const float*)d_in[5];
    const float* whh_eps = (const float*)d_in[6];
    const float* bmu     = (const float*)d_in[7];
    const float* brho    = (const float*)d_in[8];
    const float* beps    = (const float*)d_in[9];
    const float* wlin    = (const float*)d_in[10];
    const float* blin    = (const float*)d_in[11];
    float* out = (float*)d_out;

    const int B = in_sizes[0] / (TSEQ * DIN);   // 256

    blstm_fused<<<B, 128, 0, stream>>>(x, wih_mu, wih_rho, wih_eps,
                                       whh_mu, whh_rho, whh_eps,
                                       bmu, brho, beps, wlin, blin, out);
}

// Round 14
// 393.264 us; speedup vs baseline: 2.3501x; 1.0075x over previous
//
#include <hip/hip_runtime.h>
#include <hip/hip_bf16.h>
#include <math.h>

#define TSEQ 2048
#define DIN  32
#define HID  20
#define G4   80
#define TILE 16
#define NT   (TSEQ / TILE)
#define HSTR 68                 // padded hist row stride (floats), 16B-aligned rows
#define L2E  1.44269504088896340736f

typedef float v2f __attribute__((ext_vector_type(2)));
typedef unsigned int uint2v __attribute__((ext_vector_type(2)));
typedef _Float16 h2v __attribute__((ext_vector_type(2)));

#if __has_builtin(__builtin_amdgcn_exp2f)
#define EXP2(x) __builtin_amdgcn_exp2f(x)
#else
#define EXP2(x) __expf((x) * 0.69314718055994531f)
#endif

#if __has_builtin(__builtin_amdgcn_fdot2) && \
    (__has_builtin(__builtin_amdgcn_mov_dpp) || __has_builtin(__builtin_amdgcn_update_dpp)) && \
    __has_builtin(__builtin_amdgcn_perm)
#define USE_FDOT2 1
#else
#define USE_FDOT2 0
#endif

__device__ __forceinline__ float rl(float v, int l) {
    return __int_as_float(__builtin_amdgcn_readlane(__float_as_int(v), l));
}

__device__ __forceinline__ float sig2(float xs) {   // 1/(1+2^-xs), xs pre-scaled by log2e
    return __builtin_amdgcn_rcpf(1.0f + EXP2(-xs));
}

// cross-half (lane ^ 32) exchange via the gfx950 BUILTIN (hazard-safe; the
// inline-asm form caused the non-deterministic R3/R5/R6/R9 failures — R10
// confirmed the builtin fix). Order-agnostic: r.x + r.y - v = opposite half.
__device__ __forceinline__ float xhalf(float v) {
#if __has_builtin(__builtin_amdgcn_permlane32_swap)
    uint2v r = __builtin_amdgcn_permlane32_swap(__float_as_uint(v),
                                                __float_as_uint(v),
                                                false, false);
    return (__uint_as_float(r.x) + __uint_as_float(r.y)) - v;
#else
    return __shfl_xor(v, 32);
#endif
}

__device__ __forceinline__ float samp(const float* mu, const float* rho,
                                      const float* eps, int i) {
    return mu[i] + log1pf(__expf(rho[i])) * eps[i];
}

// quad_perm [1,1,3,3]: even lanes receive their odd neighbor's value (VALU DPP)
__device__ __forceinline__ int dpp_odd_to_even(int v) {
#if __has_builtin(__builtin_amdgcn_mov_dpp)
    return __builtin_amdgcn_mov_dpp(v, 0xF5, 0xf, 0xf, false);
#else
    return __builtin_amdgcn_update_dpp(0, v, 0xF5, 0xf, 0xf, false);
#endif
}

// R7 producer (proven) + consumer with f16 dot2 recurrence dot:
//   h-pack: cvt_f16 + DPP quad_perm + v_perm  (3 insts, lane-local)
//   10 readlanes (packed pairs) + 20 v_dot2_f32_f16  (was 20 rl + 40 fma)
__global__ __launch_bounds__(128, 1) void blstm_fused(
    const float* __restrict__ x,
    const float* __restrict__ wih_mu, const float* __restrict__ wih_rho, const float* __restrict__ wih_eps,
    const float* __restrict__ whh_mu, const float* __restrict__ whh_rho, const float* __restrict__ whh_eps,
    const float* __restrict__ bmu,    const float* __restrict__ brho,    const float* __restrict__ beps,
    const float* __restrict__ wlin,   const float* __restrict__ blin,
    float* __restrict__ out)
{
    __shared__ __align__(16) float lds_xg[2][TILE * G4];  // double-buffered xg tiles (permuted)
    __shared__ __align__(16) float lds_x[TILE * DIN];     // producer-private x stage
    __shared__ __align__(16) float hist[64 * HSTR];       // padded h ring

    const int tid  = threadIdx.x;
    const int lane = tid & 63;
    const int b    = blockIdx.x;
    const float* xrow = x + (size_t)b * TSEQ * DIN;
    float* outp = out + (size_t)b * TSEQ;

    if (tid < 64) {
        // ======================= CONSUMER (recurrence) =======================
        const int p  = lane >> 5;                  // 0: (i,f) cols; 1: (g,o) cols
        const int k  = lane & 31;
        const int ke = (k < HID) ? k : (HID - 1);  // junk lanes mirror unit 19
        const int g1 = p * 40 + ke;                // i_k or g_k
        const int g2 = g1 + HID;                   // f_k or o_k
        const float sc1 = (p ? 2.0f : 1.0f) * L2E;
        const float sc2 = L2E;
        // act1 constants with 2*L2E folded into the HIGH-lane tanh output:
        //   low:  act1 = sig(i);  high: act1 = 2*L2E*tanh(g)
        const float aAct2 = p ? (4.0f * L2E) : 1.0f;
        const float cAct2 = p ? (-2.0f * L2E) : 0.0f;

#if USE_FDOT2
        // f16 j-pair weights: w1h[m] = {w1[2m], w1[2m+1]} (scales folded)
        h2v w1h[HID / 2], w2h[HID / 2];
#pragma unroll
        for (int m = 0; m < HID / 2; ++m) {
            const int je = 2 * m, jo = 2 * m + 1;
            w1h[m] = (h2v){ (_Float16)(samp(whh_mu, whh_rho, whh_eps, je * G4 + g1) * sc1),
                            (_Float16)(samp(whh_mu, whh_rho, whh_eps, jo * G4 + g1) * sc1) };
            w2h[m] = (h2v){ (_Float16)(samp(whh_mu, whh_rho, whh_eps, je * G4 + g2) * sc2),
                            (_Float16)(samp(whh_mu, whh_rho, whh_eps, jo * G4 + g2) * sc2) };
        }
#else
        v2f w12e[HID / 2], w12o[HID / 2];
#pragma unroll
        for (int jj = 0; jj < HID / 2; ++jj) {
            const int je = 2 * jj, jo = 2 * jj + 1;
            w12e[jj] = (v2f){ samp(whh_mu, whh_rho, whh_eps, je * G4 + g1) * sc1,
                              samp(whh_mu, whh_rho, whh_eps, je * G4 + g2) * sc2 };
            w12o[jj] = (v2f){ samp(whh_mu, whh_rho, whh_eps, jo * G4 + g1) * sc1,
                              samp(whh_mu, whh_rho, whh_eps, jo * G4 + g2) * sc2 };
        }
#endif
        const int coff = p * 40 + ke * 2;

        float h = 0.0f, c = 0.0f;                  // c is c' = 2*L2E*c_true
        for (int kt = 0; kt < NT; ++kt) {
            __syncthreads();                       // tile kt ready
            const float* xg = lds_xg[kt & 1];
            v2f xgr[TILE];
#pragma unroll
            for (int r = 0; r < TILE; ++r)
                xgr[r] = *(const v2f*)&xg[r * G4 + coff];

#pragma unroll
            for (int ti = 0; ti < TILE; ++ti) {
                float d1, d2;
#if USE_FDOT2
                // pack h -> f16 pairs on even lanes: {h_2m (own), h_2m+1 (dpp)}
                const _Float16 hf = (_Float16)h;
                const unsigned cv = (unsigned)__builtin_bit_cast(unsigned short, hf);
                const int      sh = dpp_odd_to_even((int)cv);
                const unsigned pk = __builtin_amdgcn_perm((unsigned)sh, cv, 0x05040100u);

                int hp[HID / 2];
#pragma unroll
                for (int m = 0; m < HID / 2; ++m)
                    hp[m] = __builtin_amdgcn_readlane((int)pk, 2 * m);

                float d1a = xgr[ti].x, d2a = xgr[ti].y;
                float d1b = 0.0f, d2b = 0.0f;
#pragma unroll
                for (int m = 0; m < 5; ++m) {
                    const h2v hv = __builtin_bit_cast(h2v, hp[m]);
                    d1a = __builtin_amdgcn_fdot2(hv, w1h[m], d1a, false);
                    d2a = __builtin_amdgcn_fdot2(hv, w2h[m], d2a, false);
                }
#pragma unroll
                for (int m = 5; m < HID / 2; ++m) {
                    const h2v hv = __builtin_bit_cast(h2v, hp[m]);
                    d1b = __builtin_amdgcn_fdot2(hv, w1h[m], d1b, false);
                    d2b = __builtin_amdgcn_fdot2(hv, w2h[m], d2b, false);
                }
                d1 = d1a + d1b;
                d2 = d2a + d2b;
#else
                float hj[HID];
#pragma unroll
                for (int j = 0; j < HID; ++j) hj[j] = rl(h, j);

                v2f d12a = xgr[ti];
                v2f d12b = (v2f){0.0f, 0.0f};
#pragma unroll
                for (int jj = 0; jj < HID / 2; ++jj) {
                    d12a = __builtin_elementwise_fma(
                        (v2f){hj[2 * jj], hj[2 * jj]}, w12e[jj], d12a);
                    d12b = __builtin_elementwise_fma(
                        (v2f){hj[2 * jj + 1], hj[2 * jj + 1]}, w12o[jj], d12b);
                }
                const v2f d12 = d12a + d12b;
                d1 = d12.x;
                d2 = d12.y;
#endif

                const float s1   = sig2(d1);                // sig(i) / sig(2g)
                const float act1 = fmaf(s1, aAct2, cAct2);  // sig(i) / 2L2E*tanh(g)
                const float act2 = sig2(d2);                // sig(f) / sig(o)

                const float og1 = xhalf(act1);              // low: 2L2E*tanh(g)
                const float og2 = xhalf(act2);              // low: sig(o)

                c = fmaf(act2, c, act1 * og1);              // c' = f*c' + i*2L2E*tanh(g)
                const float tc = fmaf(2.0f, sig2(c), -1.0f);// tanh(c_true)
                h = og2 * tc;                               // low: o * tanh(c)

                const int t = kt * TILE + ti;
                hist[(t & 63) * HSTR + lane] = h;           // unconditional, padded
            }
        }
        __syncthreads();                           // expose last tile's hist
    } else {
        // ================= PRODUCER (R7-proven, byte-identical) =================
        const int cA = lane;                       // columns 0..63
        const int cB = 64 + (lane & 15);           // columns 64..79 ('o' tail)
        const float scA = ((cA >= 40 && cA < 60) ? 2.0f : 1.0f) * L2E;
        const float scB = L2E;

        float wA[DIN], wB[DIN];
#pragma unroll
        for (int d = 0; d < DIN; ++d) {
            wA[d] = samp(wih_mu, wih_rho, wih_eps, d * G4 + cA) * scA;
            wB[d] = samp(wih_mu, wih_rho, wih_eps, d * G4 + cB) * scB;
        }
        const float biasA = samp(bmu, brho, beps, cA) * scA;
        const float biasB = samp(bmu, brho, beps, cB) * scB;

        const int posA = ((cA >= 40) ? 40 : 0) + (cA % 20) * 2 + ((cA / 20) & 1);
        const int posB = ((cB >= 40) ? 40 : 0) + (cB % 20) * 2 + ((cB / 20) & 1);
        const int qs   = (lane >> 4) * 4;          // dotB step group

        float wl[HID];
#pragma unroll
        for (int j = 0; j < HID; ++j) wl[j] = wlin[j];
        const float bl = blin[0];

        auto produce = [&](int kt) {
            const float* xu = xrow + kt * TILE * DIN;
            float* xgb = lds_xg[kt & 1];
            // stage x tile (coalesced float4 -> L1/L2 prewarm + dotB source)
            {
                const float4* src = (const float4*)xu;
                float4 v0 = src[lane * 2 + 0];
                float4 v1 = src[lane * 2 + 1];
                ((float4*)lds_x)[lane * 2 + 0] = v0;
                ((float4*)lds_x)[lane * 2 + 1] = v1;
            }
            // dotA: uniform x (scalarizable s_loads), 16 steps, 64 columns
#pragma unroll
            for (int s = 0; s < TILE; ++s) {
                float a0 = 0.0f, a1 = 0.0f;
#pragma unroll
                for (int d = 0; d < 16; ++d) {
                    a0 = fmaf(xu[s * DIN + d],      wA[d],      a0);
                    a1 = fmaf(xu[s * DIN + d + 16], wA[d + 16], a1);
                }
                xgb[s * G4 + posA] = biasA + a0 + a1;
            }
            // dotB: 16 extra columns, 4 steps per lane, x from LDS
#pragma unroll
            for (int jj = 0; jj < 4; ++jj) {
                const int s = qs + jj;
                const float4* xr = (const float4*)&lds_x[s * DIN];
                float a0 = 0.0f, a1 = 0.0f;
#pragma unroll
                for (int q = 0; q < 4; ++q) {
                    const float4 u0 = xr[q], u1 = xr[q + 4];
                    a0 = fmaf(u0.x, wB[q * 4 + 0],      a0);
                    a0 = fmaf(u0.y, wB[q * 4 + 1],      a0);
                    a0 = fmaf(u0.z, wB[q * 4 + 2],      a0);
                    a0 = fmaf(u0.w, wB[q * 4 + 3],      a0);
                    a1 = fmaf(u1.x, wB[16 + q * 4 + 0], a1);
                    a1 = fmaf(u1.y, wB[16 + q * 4 + 1], a1);
                    a1 = fmaf(u1.z, wB[16 + q * 4 + 2], a1);
                    a1 = fmaf(u1.w, wB[16 + q * 4 + 3], a1);
                }
                xgb[s * G4 + posB] = biasB + a0 + a1;
            }
        };

        auto flush = [&](int ft) {
            if (lane < TILE) {
                const int t = ft * TILE + lane;
                const float4* hr = (const float4*)&hist[(t & 63) * HSTR];
                const float4 r0 = hr[0], r1 = hr[1], r2 = hr[2], r3 = hr[3], r4 = hr[4];
                float acc = bl;
                acc = fmaf(r0.x, wl[0],  acc); acc = fmaf(r0.y, wl[1],  acc);
                acc = fmaf(r0.z, wl[2],  acc); acc = fmaf(r0.w, wl[3],  acc);
                acc = fmaf(r1.x, wl[4],  acc); acc = fmaf(r1.y, wl[5],  acc);
                acc = fmaf(r1.z, wl[6],  acc); acc = fmaf(r1.w, wl[7],  acc);
                acc = fmaf(r2.x, wl[8],  acc); acc = fmaf(r2.y, wl[9],  acc);
                acc = fmaf(r2.z, wl[10], acc); acc = fmaf(r2.w, wl[11], acc);
                acc = fmaf(r3.x, wl[12], acc); acc = fmaf(r3.y, wl[13], acc);
                acc = fmaf(r3.z, wl[14], acc); acc = fmaf(r3.w, wl[15], acc);
                acc = fmaf(r4.x, wl[16], acc); acc = fmaf(r4.y, wl[17], acc);
                acc = fmaf(r4.z, wl[18], acc); acc = fmaf(r4.w, wl[19], acc);
                outp[t] = acc;
            }
        };

        produce(0);
        for (int kt = 0; kt < NT; ++kt) {
            __syncthreads();                       // release tile kt
            if (kt + 1 < NT) produce(kt + 1);
            if (kt >= 1)     flush(kt - 1);
        }
        __syncthreads();                           // consumer's last tile visible
        flush(NT - 1);
    }
}

extern "C" void kernel_launch(void* const* d_in, const int* in_sizes, int n_in,
                              void* d_out, int out_size, void* d_ws, size_t ws_size,
                              hipStream_t stream) {
    const float* x       = (const float*)d_in[0];
    const float* wih_mu  = (const float*)d_in[1];
    const float* wih_rho = (const float*)d_in[2];
    const float* wih_eps = (const float*)d_in[3];
    const float* whh_mu  = (const float*)d_in[4];
    const float* whh_rho = (const float*)d_in[5];
    const float* whh_eps = (const float*)d_in[6];
    const float* bmu     = (const float*)d_in[7];
    const float* brho    = (const float*)d_in[8];
    const float* beps    = (const float*)d_in[9];
    const float* wlin    = (const float*)d_in[10];
    const float* blin    = (const float*)d_in[11];
    float* out = (float*)d_out;

    const int B = in_sizes[0] / (TSEQ * DIN);   // 256

    blstm_fused<<<B, 128, 0, stream>>>(x, wih_mu, wih_rho, wih_eps,
                                       whh_mu, whh_rho, whh_eps,
                                       bmu, brho, beps, wlin, blin, out);
}